// Round 11
// baseline (676.082 us; speedup 1.0000x reference)
//
#include <hip/hip_runtime.h>
#include <hip/hip_bf16.h>
#include <hip/hip_fp16.h>

#define NA 150000
#define NT 200000
#define E_AT 1000000
#define E_TA 1000000
#define E_AA 500000

#define CHK 4096           // edges per count/scatter block
#define P_AT 391           // ceil(NT/512)
#define P_TA 293           // ceil(NA/512)
#define P_AA 293
#define NBINS (P_AT + P_TA + P_AA)   // 977
#define CB_AT 245          // ceil(E_AT/CHK)
#define CB_TA 245
#define CB_AA 123
#define NBBIN (CB_AT + CB_TA + CB_AA)   // 613

// gather grid partition: 32 dsts per 256-thread block (8 lanes per dst)
#define GB_AT 6250         // ceil(NT/32)
#define GB_TA 4688         // ceil(NA/32)
#define GB_AA 4688

// proj grid partition: 64 nodes per 256-thread block (8 lanes per node, 2 nodes/lane)
#define GA64 2344          // ceil(NA/64)
#define GT64 3125          // NT/64
#define NB_SEM 586         // ceil(NA/256) blocks per relation for sem reduce

// fp32 weight cache offsets (in ws)
#define WO_W1   0          // 2*64*32 = 4096
#define WO_B1   4096       // 64
#define WO_W23  4160       // 4096
#define WO_B23  8256       // 128
#define WO_AS   8384       // 288
#define WO_AD   8672       // 288
#define WO_KW   8960       // 3072
#define WO_KB   12032      // 96
#define WO_Q    12128      // 96
#define WO_LW   12224      // 64
#define WO_LB   12288      // 2

// ---------- dtype-flexible load: flag==1 -> fp32, flag==0 -> bf16 ----------
__device__ __forceinline__ float ldf(const void* p, long i, int f32) {
    if (f32) return ((const float*)p)[i];
    unsigned int u = ((const unsigned short*)p)[i];
    union { unsigned int ui; float f; } v; v.ui = u << 16;
    return v.f;
}
__device__ __forceinline__ float bf2f(unsigned short u) {
    union { unsigned int ui; float f; } v; v.ui = ((unsigned int)u) << 16;
    return v.f;
}
__device__ __forceinline__ float h2f(unsigned short u) {
    return __half2float(__ushort_as_half(u));
}
__device__ __forceinline__ unsigned short f2h(float x) {
    return __half_as_ushort(__float2half(x));
}
__device__ __forceinline__ float ftanh(float x) {
    x = fminf(fmaxf(x, -9.f), 9.f);
    float e = __expf(2.f * x);
    return (e - 1.f) / (e + 1.f);
}

// ========== count + init (one dispatch; blocks 0..NBBIN-1 count, block NBBIN inits) ==========
// Count path: per-dst degree (global atomics over deg arrays, pre-zeroed by memset)
// + per-bin totals via LDS histogram -> gcnt. Init path: dtype detect + fp32
// weight cache + sem zero.
__global__ __launch_bounds__(256) void k_countinit(
        const int* __restrict__ eat_d, const int* __restrict__ eta_d,
        const int* __restrict__ eaa_d,
        int* __restrict__ gcnt, int* __restrict__ deg_at,
        int* __restrict__ deg_ta, int* __restrict__ deg_aa,
        const void* __restrict__ x,
        const void* __restrict__ pW1, const void* __restrict__ pb1,
        const void* __restrict__ pW23, const void* __restrict__ pb23,
        const void* __restrict__ attS, const void* __restrict__ attD,
        const void* __restrict__ kW, const void* __restrict__ kb,
        const void* __restrict__ qv, const void* __restrict__ linW,
        const void* __restrict__ linb,
        float* __restrict__ wts, int* __restrict__ flagp, float* __restrict__ sem) {
    __shared__ int hist[P_AT];
    const int t = threadIdx.x;
    int b = blockIdx.x;
    if (b >= NBBIN) {
        // ---------------- init path ----------------
        if (t == 0) hist[0] = 0;
        __syncthreads();
        const unsigned short* u = (const unsigned short*)x;
        int wild = 0;
        for (int i = t; i < 4096; i += 256) {
            unsigned short v = u[i];
            int e = (v >> 7) & 0xFF;
            if (e > 133 || (e != 0 && e < 100)) wild++;
            else if (e == 0 && (v & 0x7F)) wild++;
        }
        atomicAdd(&hist[0], wild);
        __syncthreads();
        const int f32 = (hist[0] > 1024) ? 1 : 0;
        if (t == 0) *flagp = f32;
        if (t < 8) sem[t] = 0.f;
        for (int i = t; i < 4096; i += 256) wts[WO_W1 + i]  = ldf(pW1, i, f32);
        for (int i = t; i < 64;   i += 256) wts[WO_B1 + i]  = ldf(pb1, i, f32);
        for (int i = t; i < 4096; i += 256) wts[WO_W23 + i] = ldf(pW23, i, f32);
        for (int i = t; i < 128;  i += 256) wts[WO_B23 + i] = ldf(pb23, i, f32);
        for (int i = t; i < 288;  i += 256) wts[WO_AS + i]  = ldf(attS, i, f32);
        for (int i = t; i < 288;  i += 256) wts[WO_AD + i]  = ldf(attD, i, f32);
        for (int i = t; i < 3072; i += 256) wts[WO_KW + i]  = ldf(kW, i, f32);
        for (int i = t; i < 96;   i += 256) wts[WO_KB + i]  = ldf(kb, i, f32);
        for (int i = t; i < 96;   i += 256) wts[WO_Q + i]   = ldf(qv, i, f32);
        for (int i = t; i < 64;   i += 256) wts[WO_LW + i]  = ldf(linW, i, f32);
        for (int i = t; i < 2;    i += 256) wts[WO_LB + i]  = ldf(linb, i, f32);
        return;
    }
    // ---------------- count path ----------------
    const int* dst; int E, P, seg; int* deg;
    if (b < CB_AT)              { dst = eat_d; E = E_AT; P = P_AT; seg = 0;            deg = deg_at; }
    else if (b < CB_AT + CB_TA) { b -= CB_AT;  dst = eta_d; E = E_TA; P = P_TA; seg = P_AT;        deg = deg_ta; }
    else                        { b -= CB_AT + CB_TA; dst = eaa_d; E = E_AA; P = P_AA; seg = P_AT + P_TA; deg = deg_aa; }
    long e0 = (long)b * CHK;
    for (int i = t; i < P; i += 256) hist[i] = 0;
    __syncthreads();
    for (int k = 0; k < CHK; k += 256) {
        long e = e0 + k + t;
        if (e < E) {
            int d = dst[e];
            atomicAdd(&deg[d], 1);
            atomicAdd(&hist[d >> 9], 1);
        }
    }
    __syncthreads();
    for (int i = t; i < P; i += 256)
        if (hist[i]) atomicAdd(&gcnt[seg + i], hist[i]);
}

// ========== per-bin off/cur from deg: bin base via gcnt prefix + LDS scan ==========
__global__ __launch_bounds__(256) void k_offscan(
        const int* __restrict__ gcnt,
        const int* __restrict__ deg_at, const int* __restrict__ deg_ta,
        const int* __restrict__ deg_aa,
        int* __restrict__ off_at, int* __restrict__ off_ta, int* __restrict__ off_aa,
        int* __restrict__ cur_at, int* __restrict__ cur_ta, int* __restrict__ cur_aa) {
    __shared__ int sa[512], sb[512];
    __shared__ int red[4];
    int b = blockIdx.x, t = threadIdx.x;
    const int* deg; int* off; int* cur; int N, bin, seg;
    if (b < P_AT)              { deg = deg_at; off = off_at; cur = cur_at; N = NT; bin = b;                seg = 0; }
    else if (b < P_AT + P_TA)  { deg = deg_ta; off = off_ta; cur = cur_ta; N = NA; bin = b - P_AT;         seg = P_AT; }
    else                       { deg = deg_aa; off = off_aa; cur = cur_aa; N = NA; bin = b - P_AT - P_TA;  seg = P_AT + P_TA; }
    if (b == 0 && t == 0) { off_at[NT] = E_AT; off_ta[NA] = E_TA; off_aa[NA] = E_AA; }
    // base = exclusive prefix of gcnt over this relation's bins
    int part = 0;
    for (int i = t; i < bin; i += 256) part += gcnt[seg + i];
    for (int o = 32; o > 0; o >>= 1) part += __shfl_xor(part, o, 64);
    if ((t & 63) == 0) red[t >> 6] = part;
    for (int i = t; i < 512; i += 256) {
        int gd = bin * 512 + i;
        sa[i] = (gd < N) ? deg[gd] : 0;
    }
    __syncthreads();
    const int base = red[0] + red[1] + red[2] + red[3];
    int* in = sa; int* out = sb;
    for (int o = 1; o < 512; o <<= 1) {
        for (int i = t; i < 512; i += 256)
            out[i] = in[i] + (i >= o ? in[i - o] : 0);
        __syncthreads();
        int* tmp = in; in = out; out = tmp;
    }
    for (int i = t; i < 512; i += 256) {
        int excl = i ? in[i - 1] : 0;
        int gd = bin * 512 + i;
        if (gd < N) { off[gd] = base + excl; cur[gd] = base + excl; }
    }
}

// ========== MERGED csr scatter + layer-1 projection ==========
// blocks [0,NBBIN): scatter edges directly into csr via atomicAdd(cur[dst])
// (replaces the old slot-staging + binsort pass). blocks [NBBIN,...): layer-1
// projection, 8 lanes/node with 2-NODE register blocking: lane q computes the
// q-quad for nodes g and g+32, sharing the 4 W reads -> per-node LDS reads
// drop 80->48 and two independent FMA chains double ILP.
__global__ __launch_bounds__(256) void k_projscat(
        const void* __restrict__ Xa, const void* __restrict__ Xt,
        const float* __restrict__ W, const float* __restrict__ Bv,
        unsigned short* __restrict__ Ha, unsigned short* __restrict__ Ht,
        const float* __restrict__ attD,
        float* __restrict__ ad0, float* __restrict__ ad1, float* __restrict__ ad2,
        const int* __restrict__ flagp,
        const int* __restrict__ eat_s, const int* __restrict__ eat_d,
        const int* __restrict__ eta_s, const int* __restrict__ eta_d,
        const int* __restrict__ eaa_s, const int* __restrict__ eaa_d,
        int* __restrict__ cur_at, int* __restrict__ cur_ta, int* __restrict__ cur_aa,
        int* __restrict__ csr_at, int* __restrict__ csr_ta, int* __restrict__ csr_aa) {
    __shared__ float smem[6400];     // proj: Xs[64*68]=4352 + Wl[64*32]=2048
    const int t = threadIdx.x;
    int b = blockIdx.x;
    if (b < NBBIN) {
        // ---------------- scatter path ----------------
        const int *src, *dst; int E; int* cur; int* csr;
        if (b < CB_AT)              { src = eat_s; dst = eat_d; E = E_AT; cur = cur_at; csr = csr_at; }
        else if (b < CB_AT + CB_TA) { b -= CB_AT;  src = eta_s; dst = eta_d; E = E_TA; cur = cur_ta; csr = csr_ta; }
        else                        { b -= CB_AT + CB_TA; src = eaa_s; dst = eaa_d; E = E_AA; cur = cur_aa; csr = csr_aa; }
        long e0 = (long)b * CHK;
        for (int k = 0; k < CHK; k += 256) {
            long e = e0 + k + t;
            if (e < E) {
                int d = dst[e];
                int pos = atomicAdd(&cur[d], 1);
                csr[pos] = src[e];
            }
        }
        return;
    }
    // ---------------- proj path (K=64, layer 1, 2 nodes/thread) ----------------
    b -= NBBIN;
    constexpr int K = 64, XS = K + 4, CPR = K / 4, TOT4 = 64 * CPR;
    float* Xs = smem;                // 64*68 = 4352
    float* Wl = smem + 4352;         // 64*32 = 2048
    const bool isA = b < GA64;
    const int bb = isA ? b : b - GA64;
    const int N = isA ? NA : NT;
    const int wOff = isA ? 0 : 2048;
    const int bOff = isA ? 0 : 32;
    const long n0 = (long)bb * 64;
    for (int i = t; i < K * 32; i += 256) Wl[i] = W[wOff + i];
    {
        const void* X = isA ? Xa : Xt;
        const int f32 = *flagp;
        if (f32) {
            const float* Xf = (const float*)X;
            for (int i = t; i < TOT4; i += 256) {
                int r = i / CPR, c = (i & (CPR - 1)) * 4;
                long gr = n0 + r; if (gr >= N) gr = N - 1;
                *(float4*)&Xs[r * XS + c] = *(const float4*)&Xf[gr * K + c];
            }
        } else {
            const unsigned short* Xh = (const unsigned short*)X;
            for (int i = t; i < TOT4; i += 256) {
                int r = i / CPR, c = (i & (CPR - 1)) * 4;
                long gr = n0 + r; if (gr >= N) gr = N - 1;
                ushort4 v = *(const ushort4*)&Xh[gr * K + c];
                float4 o;
                o.x = bf2f(v.x); o.y = bf2f(v.y); o.z = bf2f(v.z); o.w = bf2f(v.w);
                *(float4*)&Xs[r * XS + c] = o;
            }
        }
    }
    __syncthreads();
    const int g = t >> 3, q = t & 7;
    const long nA = n0 + g, nB = n0 + g + 32;
    float A0 = Bv[bOff + q * 4 + 0], A1 = Bv[bOff + q * 4 + 1];
    float A2 = Bv[bOff + q * 4 + 2], A3 = Bv[bOff + q * 4 + 3];
    float B0 = A0, B1 = A1, B2 = A2, B3 = A3;
#pragma unroll 2
    for (int k4 = 0; k4 < K; k4 += 4) {
        float4 xa = *(const float4*)&Xs[g * XS + k4];
        float4 xb = *(const float4*)&Xs[(g + 32) * XS + k4];
        float4 w0 = *(const float4*)&Wl[(k4 + 0) * 32 + q * 4];
        float4 w1 = *(const float4*)&Wl[(k4 + 1) * 32 + q * 4];
        float4 w2 = *(const float4*)&Wl[(k4 + 2) * 32 + q * 4];
        float4 w3 = *(const float4*)&Wl[(k4 + 3) * 32 + q * 4];
        A0 = fmaf(xa.x, w0.x, A0); A1 = fmaf(xa.x, w0.y, A1);
        A2 = fmaf(xa.x, w0.z, A2); A3 = fmaf(xa.x, w0.w, A3);
        B0 = fmaf(xb.x, w0.x, B0); B1 = fmaf(xb.x, w0.y, B1);
        B2 = fmaf(xb.x, w0.z, B2); B3 = fmaf(xb.x, w0.w, B3);
        A0 = fmaf(xa.y, w1.x, A0); A1 = fmaf(xa.y, w1.y, A1);
        A2 = fmaf(xa.y, w1.z, A2); A3 = fmaf(xa.y, w1.w, A3);
        B0 = fmaf(xb.y, w1.x, B0); B1 = fmaf(xb.y, w1.y, B1);
        B2 = fmaf(xb.y, w1.z, B2); B3 = fmaf(xb.y, w1.w, B3);
        A0 = fmaf(xa.z, w2.x, A0); A1 = fmaf(xa.z, w2.y, A1);
        A2 = fmaf(xa.z, w2.z, A2); A3 = fmaf(xa.z, w2.w, A3);
        B0 = fmaf(xb.z, w2.x, B0); B1 = fmaf(xb.z, w2.y, B1);
        B2 = fmaf(xb.z, w2.z, B2); B3 = fmaf(xb.z, w2.w, B3);
        A0 = fmaf(xa.w, w3.x, A0); A1 = fmaf(xa.w, w3.y, A1);
        A2 = fmaf(xa.w, w3.z, A2); A3 = fmaf(xa.w, w3.w, A3);
        B0 = fmaf(xb.w, w3.x, B0); B1 = fmaf(xb.w, w3.y, B1);
        B2 = fmaf(xb.w, w3.z, B2); B3 = fmaf(xb.w, w3.w, B3);
    }
    const int hh = q >> 1;
    const int ai = q * 4;            // lBase = 0 for layer 1
    unsigned short* Hh = isA ? Ha : Ht;
    if (nA < N) {
        unsigned int p01 = (unsigned)f2h(A0) | ((unsigned)f2h(A1) << 16);
        unsigned int p23 = (unsigned)f2h(A2) | ((unsigned)f2h(A3) << 16);
        *(uint2*)&Hh[nA * 32 + q * 4] = make_uint2(p01, p23);
        if (isA) {
            float p1 = A0 * attD[ai + 32] + A1 * attD[ai + 33]
                     + A2 * attD[ai + 34] + A3 * attD[ai + 35];
            float p2 = A0 * attD[ai + 64] + A1 * attD[ai + 65]
                     + A2 * attD[ai + 66] + A3 * attD[ai + 67];
            float s1 = p1 + __shfl_xor(p1, 1);
            float s2 = p2 + __shfl_xor(p2, 1);
            if (!(q & 1)) { ad1[nA * 4 + hh] = s1; ad2[nA * 4 + hh] = s2; }
        } else {
            float p0 = A0 * attD[ai] + A1 * attD[ai + 1]
                     + A2 * attD[ai + 2] + A3 * attD[ai + 3];
            float s0 = p0 + __shfl_xor(p0, 1);
            if (!(q & 1)) ad0[nA * 4 + hh] = s0;
        }
    }
    if (nB < N) {
        unsigned int p01 = (unsigned)f2h(B0) | ((unsigned)f2h(B1) << 16);
        unsigned int p23 = (unsigned)f2h(B2) | ((unsigned)f2h(B3) << 16);
        *(uint2*)&Hh[nB * 32 + q * 4] = make_uint2(p01, p23);
        if (isA) {
            float p1 = B0 * attD[ai + 32] + B1 * attD[ai + 33]
                     + B2 * attD[ai + 34] + B3 * attD[ai + 35];
            float p2 = B0 * attD[ai + 64] + B1 * attD[ai + 65]
                     + B2 * attD[ai + 66] + B3 * attD[ai + 67];
            float s1 = p1 + __shfl_xor(p1, 1);
            float s2 = p2 + __shfl_xor(p2, 1);
            if (!(q & 1)) { ad1[nB * 4 + hh] = s1; ad2[nB * 4 + hh] = s2; }
        } else {
            float p0 = B0 * attD[ai] + B1 * attD[ai + 1]
                     + B2 * attD[ai + 2] + B3 * attD[ai + 3];
            float s0 = p0 + __shfl_xor(p0, 1);
            if (!(q & 1)) ad0[nB * 4 + hh] = s0;
        }
    }
}

// ========== layers 2/3 projection (K=32, 2 nodes/thread, inline semantic attn) ==========
__global__ __launch_bounds__(256) void k_proj2(
        const float* __restrict__ O1, const float* __restrict__ Ot,
        const float* __restrict__ O2, const float* __restrict__ semL,
        const float* __restrict__ W, int wOffA, int wOffT,
        const float* __restrict__ Bv, int bOffA, int bOffT,
        unsigned short* __restrict__ Ha, unsigned short* __restrict__ Ht,
        const float* __restrict__ attD, int lBase,
        float* __restrict__ ad0, float* __restrict__ ad1, float* __restrict__ ad2) {
    constexpr int K = 32, XS = K + 4, CPR = K / 4, TOT4 = 64 * CPR;
    __shared__ float Xs[64 * XS];
    __shared__ float Wl[K * 32];
    const int t = threadIdx.x;
    const bool isA = blockIdx.x < GA64;
    const int bb = isA ? (int)blockIdx.x : (int)blockIdx.x - GA64;
    const int N = isA ? NA : NT;
    const int wOff = isA ? wOffA : wOffT;
    const int bOff = isA ? bOffA : bOffT;
    const long n0 = (long)bb * 64;
    for (int i = t; i < K * 32; i += 256) Wl[i] = W[wOff + i];
    if (isA) {
        float s0 = semL[0] * (1.0f / NA), s1 = semL[1] * (1.0f / NA);
        float m = fmaxf(s0, s1);
        float e0 = __expf(s0 - m), e1 = __expf(s1 - m);
        float inv = 1.f / (e0 + e1);
        const float w0 = e0 * inv, w1 = e1 * inv;
        for (int i = t; i < TOT4; i += 256) {
            int r = i / CPR, c = (i & (CPR - 1)) * 4;
            long gr = n0 + r; if (gr >= N) gr = N - 1;
            float4 va = *(const float4*)&O1[gr * K + c];
            float4 vb = *(const float4*)&O2[gr * K + c];
            float4 o;
            o.x = fmaxf(w0 * va.x + w1 * vb.x, 0.f);
            o.y = fmaxf(w0 * va.y + w1 * vb.y, 0.f);
            o.z = fmaxf(w0 * va.z + w1 * vb.z, 0.f);
            o.w = fmaxf(w0 * va.w + w1 * vb.w, 0.f);
            *(float4*)&Xs[r * XS + c] = o;
        }
    } else {
        for (int i = t; i < TOT4; i += 256) {
            int r = i / CPR, c = (i & (CPR - 1)) * 4;
            long gr = n0 + r; if (gr >= N) gr = N - 1;
            *(float4*)&Xs[r * XS + c] = *(const float4*)&Ot[gr * K + c];
        }
    }
    __syncthreads();
    const int g = t >> 3, q = t & 7;
    const long nA = n0 + g, nB = n0 + g + 32;
    float A0 = Bv[bOff + q * 4 + 0], A1 = Bv[bOff + q * 4 + 1];
    float A2 = Bv[bOff + q * 4 + 2], A3 = Bv[bOff + q * 4 + 3];
    float B0 = A0, B1 = A1, B2 = A2, B3 = A3;
#pragma unroll 2
    for (int k4 = 0; k4 < K; k4 += 4) {
        float4 xa = *(const float4*)&Xs[g * XS + k4];
        float4 xb = *(const float4*)&Xs[(g + 32) * XS + k4];
        float4 w0 = *(const float4*)&Wl[(k4 + 0) * 32 + q * 4];
        float4 w1 = *(const float4*)&Wl[(k4 + 1) * 32 + q * 4];
        float4 w2 = *(const float4*)&Wl[(k4 + 2) * 32 + q * 4];
        float4 w3 = *(const float4*)&Wl[(k4 + 3) * 32 + q * 4];
        A0 = fmaf(xa.x, w0.x, A0); A1 = fmaf(xa.x, w0.y, A1);
        A2 = fmaf(xa.x, w0.z, A2); A3 = fmaf(xa.x, w0.w, A3);
        B0 = fmaf(xb.x, w0.x, B0); B1 = fmaf(xb.x, w0.y, B1);
        B2 = fmaf(xb.x, w0.z, B2); B3 = fmaf(xb.x, w0.w, B3);
        A0 = fmaf(xa.y, w1.x, A0); A1 = fmaf(xa.y, w1.y, A1);
        A2 = fmaf(xa.y, w1.z, A2); A3 = fmaf(xa.y, w1.w, A3);
        B0 = fmaf(xb.y, w1.x, B0); B1 = fmaf(xb.y, w1.y, B1);
        B2 = fmaf(xb.y, w1.z, B2); B3 = fmaf(xb.y, w1.w, B3);
        A0 = fmaf(xa.z, w2.x, A0); A1 = fmaf(xa.z, w2.y, A1);
        A2 = fmaf(xa.z, w2.z, A2); A3 = fmaf(xa.z, w2.w, A3);
        B0 = fmaf(xb.z, w2.x, B0); B1 = fmaf(xb.z, w2.y, B1);
        B2 = fmaf(xb.z, w2.z, B2); B3 = fmaf(xb.z, w2.w, B3);
        A0 = fmaf(xa.w, w3.x, A0); A1 = fmaf(xa.w, w3.y, A1);
        A2 = fmaf(xa.w, w3.z, A2); A3 = fmaf(xa.w, w3.w, A3);
        B0 = fmaf(xb.w, w3.x, B0); B1 = fmaf(xb.w, w3.y, B1);
        B2 = fmaf(xb.w, w3.z, B2); B3 = fmaf(xb.w, w3.w, B3);
    }
    const int hh = q >> 1;
    const int ai = lBase + q * 4;
    unsigned short* Hh = isA ? Ha : Ht;
    if (nA < N) {
        unsigned int p01 = (unsigned)f2h(A0) | ((unsigned)f2h(A1) << 16);
        unsigned int p23 = (unsigned)f2h(A2) | ((unsigned)f2h(A3) << 16);
        *(uint2*)&Hh[nA * 32 + q * 4] = make_uint2(p01, p23);
        if (isA) {
            float p1 = A0 * attD[ai + 32] + A1 * attD[ai + 33]
                     + A2 * attD[ai + 34] + A3 * attD[ai + 35];
            float p2 = A0 * attD[ai + 64] + A1 * attD[ai + 65]
                     + A2 * attD[ai + 66] + A3 * attD[ai + 67];
            float s1 = p1 + __shfl_xor(p1, 1);
            float s2 = p2 + __shfl_xor(p2, 1);
            if (!(q & 1)) { ad1[nA * 4 + hh] = s1; ad2[nA * 4 + hh] = s2; }
        } else {
            float p0 = A0 * attD[ai] + A1 * attD[ai + 1]
                     + A2 * attD[ai + 2] + A3 * attD[ai + 3];
            float s0 = p0 + __shfl_xor(p0, 1);
            if (!(q & 1)) ad0[nA * 4 + hh] = s0;
        }
    }
    if (nB < N) {
        unsigned int p01 = (unsigned)f2h(B0) | ((unsigned)f2h(B1) << 16);
        unsigned int p23 = (unsigned)f2h(B2) | ((unsigned)f2h(B3) << 16);
        *(uint2*)&Hh[nB * 32 + q * 4] = make_uint2(p01, p23);
        if (isA) {
            float p1 = B0 * attD[ai + 32] + B1 * attD[ai + 33]
                     + B2 * attD[ai + 34] + B3 * attD[ai + 35];
            float p2 = B0 * attD[ai + 64] + B1 * attD[ai + 65]
                     + B2 * attD[ai + 66] + B3 * attD[ai + 67];
            float s1 = p1 + __shfl_xor(p1, 1);
            float s2 = p2 + __shfl_xor(p2, 1);
            if (!(q & 1)) { ad1[nB * 4 + hh] = s1; ad2[nB * 4 + hh] = s2; }
        } else {
            float p0 = B0 * attD[ai] + B1 * attD[ai + 1]
                     + B2 * attD[ai + 2] + B3 * attD[ai + 3];
            float s0 = p0 + __shfl_xor(p0, 1);
            if (!(q & 1)) ad0[nB * 4 + hh] = s0;
        }
    }
}

// ========== tri-relation gather: 8 lanes/dst, fp16 H, in-kernel src alpha ==========
__global__ __launch_bounds__(256) void k_gather3(
        const int* __restrict__ off_at, const int* __restrict__ csr_at,
        const int* __restrict__ off_ta, const int* __restrict__ csr_ta,
        const int* __restrict__ off_aa, const int* __restrict__ csr_aa,
        const float* __restrict__ ad0, const float* __restrict__ ad1,
        const float* __restrict__ ad2,
        const unsigned short* __restrict__ h_a, const unsigned short* __restrict__ h_t,
        float* __restrict__ o_tx, float* __restrict__ o_a1, float* __restrict__ o_a2,
        const float* __restrict__ attS, int lBase, int gbAT) {
    int b = blockIdx.x;
    const int *off, *csr;
    const float *ad_;
    const unsigned short* Hs;
    float* O;
    int N, attOff;
    if (b < gbAT) {
        off = off_at; csr = csr_at; ad_ = ad0; Hs = h_a; O = o_tx; N = NT;
        attOff = lBase;            // edge type 0 (A->T)
    } else if (b < gbAT + GB_TA) {
        b -= gbAT;
        off = off_ta; csr = csr_ta; ad_ = ad1; Hs = h_t; O = o_a1; N = NA;
        attOff = lBase + 32;       // edge type 1 (T->A)
    } else {
        b -= gbAT + GB_TA;
        off = off_aa; csr = csr_aa; ad_ = ad2; Hs = h_a; O = o_a2; N = NA;
        attOff = lBase + 64;       // edge type 2 (A->A)
    }
    const int t = threadIdx.x;
    const int q = t & 7;          // column quad 0..7
    const int hh = q >> 1;        // head
    const int n = b * 32 + (t >> 3);
    if (n >= N) return;
    const float4 aq = *(const float4*)&attS[attOff + q * 4];
    const float aq0 = aq.x, aq1 = aq.y, aq2 = aq.z, aq3 = aq.w;
    const float adv = ad_[n * 4 + hh];
    const int p0 = off[n], p1 = off[n + 1];
    float ax = 0.f, ay = 0.f, az = 0.f, aw = 0.f, se = 0.f;
    int p = p0;
    for (; p + 4 <= p1; p += 4) {
        int s0 = csr[p], s1 = csr[p + 1], s2 = csr[p + 2], s3 = csr[p + 3];
        ushort4 v0 = *(const ushort4*)&Hs[s0 * 32 + q * 4];
        ushort4 v1 = *(const ushort4*)&Hs[s1 * 32 + q * 4];
        ushort4 v2 = *(const ushort4*)&Hs[s2 * 32 + q * 4];
        ushort4 v3 = *(const ushort4*)&Hs[s3 * 32 + q * 4];
        float h00 = h2f(v0.x), h01 = h2f(v0.y), h02 = h2f(v0.z), h03 = h2f(v0.w);
        float h10 = h2f(v1.x), h11 = h2f(v1.y), h12 = h2f(v1.z), h13 = h2f(v1.w);
        float h20 = h2f(v2.x), h21 = h2f(v2.y), h22 = h2f(v2.z), h23 = h2f(v2.w);
        float h30 = h2f(v3.x), h31 = h2f(v3.y), h32 = h2f(v3.z), h33 = h2f(v3.w);
        float pt0 = h00 * aq0 + h01 * aq1 + h02 * aq2 + h03 * aq3;
        float pt1 = h10 * aq0 + h11 * aq1 + h12 * aq2 + h13 * aq3;
        float pt2 = h20 * aq0 + h21 * aq1 + h22 * aq2 + h23 * aq3;
        float pt3 = h30 * aq0 + h31 * aq1 + h32 * aq2 + h33 * aq3;
        float al0 = pt0 + __shfl_xor(pt0, 1);
        float al1 = pt1 + __shfl_xor(pt1, 1);
        float al2 = pt2 + __shfl_xor(pt2, 1);
        float al3 = pt3 + __shfl_xor(pt3, 1);
        float l0 = al0 + adv; l0 = fmaxf(l0, 0.2f * l0); float e0 = __expf(l0);
        float l1 = al1 + adv; l1 = fmaxf(l1, 0.2f * l1); float e1 = __expf(l1);
        float l2 = al2 + adv; l2 = fmaxf(l2, 0.2f * l2); float e2 = __expf(l2);
        float l3 = al3 + adv; l3 = fmaxf(l3, 0.2f * l3); float e3 = __expf(l3);
        se += e0 + e1 + e2 + e3;
        ax += e0 * h00 + e1 * h10 + e2 * h20 + e3 * h30;
        ay += e0 * h01 + e1 * h11 + e2 * h21 + e3 * h31;
        az += e0 * h02 + e1 * h12 + e2 * h22 + e3 * h32;
        aw += e0 * h03 + e1 * h13 + e2 * h23 + e3 * h33;
    }
    for (; p < p1; p++) {
        int s = csr[p];
        ushort4 v = *(const ushort4*)&Hs[s * 32 + q * 4];
        float h0 = h2f(v.x), h1 = h2f(v.y), h2 = h2f(v.z), h3 = h2f(v.w);
        float pt = h0 * aq0 + h1 * aq1 + h2 * aq2 + h3 * aq3;
        float al = pt + __shfl_xor(pt, 1);
        float l = al + adv; l = fmaxf(l, 0.2f * l);
        float e = __expf(l);
        se += e;
        ax += e * h0; ay += e * h1; az += e * h2; aw += e * h3;
    }
    const float inv = 1.f / (se + 1e-16f);
    float4 r;
    r.x = fmaxf(ax * inv, 0.f);
    r.y = fmaxf(ay * inv, 0.f);
    r.z = fmaxf(az * inv, 0.f);
    r.w = fmaxf(aw * inv, 0.f);
    *(float4*)&O[n * 32 + q * 4] = r;
}

// ---------- semantic reduce: scalar form (includes the q-dot); wave-uniform w ----------
__global__ __launch_bounds__(256) void k_sem_reduce(
        const float* __restrict__ O1, const float* __restrict__ O2,
        const float* __restrict__ kWl, const float* __restrict__ kbl,
        const float* __restrict__ qvl, float* __restrict__ semL) {
    __shared__ float w[1088];        // kW(1024) + kb(32) + qv(32)
    __shared__ float bacc;
    const int t = threadIdx.x;
    const int r = (blockIdx.x >= NB_SEM) ? 1 : 0;
    const float* O = r ? O2 : O1;
    for (int i = t; i < 1024; i += 256) w[i] = kWl[i];
    if (t < 32) w[1024 + t] = kbl[t];
    if (t >= 64 && t < 96) w[1056 + (t - 64)] = qvl[t - 64];
    if (t == 0) bacc = 0.f;
    __syncthreads();
    long n = (long)(blockIdx.x - r * NB_SEM) * 256 + t;
    float S = 0.f;
    if (n < NA) {
        float x[32];
#pragma unroll
        for (int k = 0; k < 32; k++) x[k] = O[n * 32 + k];
#pragma unroll
        for (int f = 0; f < 32; f++) {
            float acc = w[1024 + f];
#pragma unroll
            for (int k = 0; k < 32; k++) acc += x[k] * w[k * 32 + f];
            S += ftanh(acc) * w[1056 + f];
        }
    }
    for (int o = 32; o > 0; o >>= 1) S += __shfl_xor(S, o, 64);
    if ((t & 63) == 0) atomicAdd(&bacc, S);
    __syncthreads();
    if (t == 0) atomicAdd(&semL[r], bacc);
}

// ---------- fused combine + final linear (layer 3 only, inline semantic attn) ----------
__global__ void k_combine_final(const float* __restrict__ o1, const float* __restrict__ o2,
                                const float* __restrict__ semL,
                                const float* __restrict__ linW, const float* __restrict__ linb,
                                void* __restrict__ out, int N, const int* __restrict__ flagp) {
    int n = blockIdx.x * blockDim.x + threadIdx.x;
    if (n >= N) return;
    int f32 = *flagp;
    float q0 = semL[0] * (1.0f / NA), q1 = semL[1] * (1.0f / NA);
    float m = fmaxf(q0, q1);
    float e0 = __expf(q0 - m), e1 = __expf(q1 - m);
    float ai = 1.f / (e0 + e1);
    float w0 = e0 * ai, w1 = e1 * ai;
    float s0 = linb[0], s1 = linb[1];
    const float* p1 = &o1[(long)n * 32];
    const float* p2 = &o2[(long)n * 32];
#pragma unroll
    for (int f = 0; f < 32; f++) {
        float v = w0 * p1[f] + w1 * p2[f];
        v = (v > 0.f) ? v : 0.f;
        s0 += v * linW[f * 2];
        s1 += v * linW[f * 2 + 1];
    }
    if (f32) { ((float*)out)[n * 2] = s0; ((float*)out)[n * 2 + 1] = s1; }
    else {
        ((__hip_bfloat16*)out)[n * 2] = __float2bfloat16(s0);
        ((__hip_bfloat16*)out)[n * 2 + 1] = __float2bfloat16(s1);
    }
}

static inline int gblocks(long n) { return (int)((n + 255) / 256); }

extern "C" void kernel_launch(void* const* d_in, const int* in_sizes, int n_in,
                              void* d_out, int out_size, void* d_ws, size_t ws_size,
                              hipStream_t stream) {
    const void* x_addr = d_in[0];
    const void* x_tx   = d_in[1];
    const int* eat_s = (const int*)d_in[2];
    const int* eat_d = (const int*)d_in[3];
    const int* eta_s = (const int*)d_in[4];
    const int* eta_d = (const int*)d_in[5];
    const int* eaa_s = (const int*)d_in[6];
    const int* eaa_d = (const int*)d_in[7];
    const void* pW1  = d_in[8];
    const void* pb1  = d_in[9];
    const void* pW23 = d_in[10];
    const void* pb23 = d_in[11];
    const void* attS = d_in[12];
    const void* attD = d_in[13];
    const void* kW   = d_in[14];
    const void* kb   = d_in[15];
    const void* qv   = d_in[16];
    const void* linW = d_in[17];
    const void* linb = d_in[18];

    const size_t NA32 = (size_t)NA * 32, NT32 = (size_t)NT * 32;
    const size_t NA4 = (size_t)NA * 4, NT4 = (size_t)NT * 4;

    float* ws    = (float*)d_ws;
    float* h_aF  = ws;                   // fp16 rows (uses half the slot)
    float* h_tF  = h_aF + NA32;
    float* o_a1  = h_tF + NT32;
    float* o_a2  = o_a1 + NA32;
    float* o_tx  = o_a2 + NA32;
    float* ad1   = o_tx + NT32;          // TA dst alphas (addr)
    float* ad2   = ad1 + NA4;            // AA dst alphas (addr)
    float* ad0   = ad2 + NA4;            // AT dst alphas (tx)
    float* sem   = ad0 + NT4;            // 8 scalars: [2l], [2l+1] per layer
    int*   flagp = (int*)(sem + 8);
    int*   off_at = flagp + 16;          // NT+1
    int*   off_ta = off_at + (NT + 1);   // NA+1
    int*   off_aa = off_ta + (NA + 1);   // NA+1
    int*   csr_at = off_aa + (NA + 1);   // E_AT
    int*   csr_ta = csr_at + E_AT;       // E_TA
    int*   csr_aa = csr_ta + E_TA;       // E_AA
    int*   gcnt   = csr_aa + E_AA;       // 1024  (zeroed; deg follows contiguously)
    int*   deg_at = gcnt + 1024;         // NT
    int*   deg_ta = deg_at + NT;         // NA
    int*   deg_aa = deg_ta + NA;         // NA
    int*   cur_at = deg_aa + NA;         // NT
    int*   cur_ta = cur_at + NT;         // NA
    int*   cur_aa = cur_ta + NA;         // NA
    float* wts    = (float*)(cur_aa + NA);   // fp32 weight cache

    unsigned short* h_a = (unsigned short*)h_aF;
    unsigned short* h_t = (unsigned short*)h_tF;

    // zero gcnt + deg arrays (contiguous)
    (void)hipMemsetAsync(gcnt, 0, (size_t)(1024 + NT + 2 * NA) * sizeof(int), stream);

    // degree count (613 blocks) + init (1 block) in one dispatch
    k_countinit<<<NBBIN + 1, 256, 0, stream>>>(
        eat_d, eta_d, eaa_d, gcnt, deg_at, deg_ta, deg_aa,
        x_addr, pW1, pb1, pW23, pb23, attS, attD, kW, kb, qv, linW, linb,
        wts, flagp, sem);

    // off/cur from deg (replaces the old slot-staging binsort)
    k_offscan<<<NBINS, 256, 0, stream>>>(gcnt, deg_at, deg_ta, deg_aa,
                                         off_at, off_ta, off_aa,
                                         cur_at, cur_ta, cur_aa);

    // csr scatter (613 blocks) co-runs with layer-1 projection (5469 blocks)
    k_projscat<<<NBBIN + GA64 + GT64, 256, 0, stream>>>(
        x_addr, x_tx, wts + WO_W1, wts + WO_B1, h_a, h_t, wts + WO_AD,
        ad0, ad1, ad2, flagp,
        eat_s, eat_d, eta_s, eta_d, eaa_s, eaa_d,
        cur_at, cur_ta, cur_aa, csr_at, csr_ta, csr_aa);

    for (int l = 0; l < 3; l++) {
        if (l > 0) {
            int wi = (l - 1) * 2;
            k_proj2<<<GA64 + GT64, 256, 0, stream>>>(
                o_a1, o_tx, o_a2, sem + 2 * (l - 1),
                wts + WO_W23, (wi + 0) * 1024, (wi + 1) * 1024,
                wts + WO_B23, (wi + 0) * 32, (wi + 1) * 32,
                h_a, h_t, wts + WO_AD, l * 96, ad0, ad1, ad2);
        }
        const int gbAT = (l < 2) ? GB_AT : 0;   // layer-3 AT gather is dead work
        k_gather3<<<gbAT + GB_TA + GB_AA, 256, 0, stream>>>(
            off_at, csr_at, off_ta, csr_ta, off_aa, csr_aa,
            ad0, ad1, ad2, h_a, h_t, o_tx, o_a1, o_a2, wts + WO_AS, l * 96, gbAT);
        k_sem_reduce<<<2 * NB_SEM, 256, 0, stream>>>(
            o_a1, o_a2, wts + WO_KW + l * 1024, wts + WO_KB + l * 32,
            wts + WO_Q + l * 32, sem + 2 * l);
        if (l == 2) {
            k_combine_final<<<gblocks(NA), 256, 0, stream>>>(o_a1, o_a2, sem + 4,
                                                             wts + WO_LW, wts + WO_LB,
                                                             d_out, NA, flagp);
        }
    }
}

// Round 12
// 543.217 us; speedup vs baseline: 1.2446x; 1.2446x over previous
//
#include <hip/hip_runtime.h>
#include <hip/hip_bf16.h>
#include <hip/hip_fp16.h>

#define NA 150000
#define NT 200000
#define E_AT 1000000
#define E_TA 1000000
#define E_AA 500000

#define CHK 4096           // edges per bin block
#define CAP 8192           // slot capacity per bin (max bin count ~3.8K)
#define P_AT 391           // ceil(NT/512)
#define P_TA 293           // ceil(NA/512)
#define P_AA 293
#define NBINS (P_AT + P_TA + P_AA)   // 977
#define CB_AT 245          // ceil(E_AT/CHK)
#define CB_TA 245
#define CB_AA 123
#define NBBIN (CB_AT + CB_TA + CB_AA)   // 613

// gather grid partition: 32 dsts per 256-thread block (8 lanes per dst)
#define GB_AT 6250         // ceil(NT/32)
#define GB_TA 4688         // ceil(NA/32)
#define GB_AA 4688

// proj grids
#define GA32 4688          // ceil(NA/32)  (projbin layer-1 path: 32 nodes/block)
#define GT32 6250          // NT/32
#define GA64 2344          // ceil(NA/64)  (proj2: 64 nodes/block, 2 nodes/lane)
#define GT64 3125          // NT/64
#define NB_SEM 586         // ceil(NA/256) blocks per relation for sem reduce

// fp32 weight cache offsets (in ws)
#define WO_W1   0          // 2*64*32 = 4096
#define WO_B1   4096       // 64
#define WO_W23  4160       // 4096
#define WO_B23  8256       // 128
#define WO_AS   8384       // 288
#define WO_AD   8672       // 288
#define WO_KW   8960       // 3072
#define WO_KB   12032      // 96
#define WO_Q    12128      // 96
#define WO_LW   12224      // 64
#define WO_LB   12288      // 2

// ---------- dtype-flexible load: flag==1 -> fp32, flag==0 -> bf16 ----------
__device__ __forceinline__ float ldf(const void* p, long i, int f32) {
    if (f32) return ((const float*)p)[i];
    unsigned int u = ((const unsigned short*)p)[i];
    union { unsigned int ui; float f; } v; v.ui = u << 16;
    return v.f;
}
__device__ __forceinline__ float bf2f(unsigned short u) {
    union { unsigned int ui; float f; } v; v.ui = ((unsigned int)u) << 16;
    return v.f;
}
__device__ __forceinline__ float h2f(unsigned short u) {
    return __half2float(__ushort_as_half(u));
}
__device__ __forceinline__ unsigned short f2h(float x) {
    return __half_as_ushort(__float2half(x));
}
__device__ __forceinline__ float ftanh(float x) {
    x = fminf(fmaxf(x, -9.f), 9.f);
    float e = __expf(2.f * x);
    return (e - 1.f) / (e + 1.f);
}

// ---------- init: dtype detect + fp32 weight cache + gcnt/sem zero ----------
__global__ void k_init(const void* __restrict__ x,
                       const void* __restrict__ pW1, const void* __restrict__ pb1,
                       const void* __restrict__ pW23, const void* __restrict__ pb23,
                       const void* __restrict__ attS, const void* __restrict__ attD,
                       const void* __restrict__ kW, const void* __restrict__ kb,
                       const void* __restrict__ qv, const void* __restrict__ linW,
                       const void* __restrict__ linb,
                       float* __restrict__ wts, int* __restrict__ flagp,
                       int* __restrict__ gcnt, float* __restrict__ sem) {
    __shared__ int cnt;
    const int t = threadIdx.x;
    if (t == 0) cnt = 0;
    __syncthreads();
    const unsigned short* u = (const unsigned short*)x;
    int wild = 0;
    for (int i = t; i < 4096; i += 256) {
        unsigned short v = u[i];
        int e = (v >> 7) & 0xFF;
        if (e > 133 || (e != 0 && e < 100)) wild++;
        else if (e == 0 && (v & 0x7F)) wild++;
    }
    atomicAdd(&cnt, wild);
    __syncthreads();
    const int f32 = (cnt > 1024) ? 1 : 0;
    if (t == 0) *flagp = f32;
    if (t < 8) sem[t] = 0.f;
    for (int i = t; i < 1024; i += 256) gcnt[i] = 0;
    for (int i = t; i < 4096; i += 256) wts[WO_W1 + i]  = ldf(pW1, i, f32);
    for (int i = t; i < 64;   i += 256) wts[WO_B1 + i]  = ldf(pb1, i, f32);
    for (int i = t; i < 4096; i += 256) wts[WO_W23 + i] = ldf(pW23, i, f32);
    for (int i = t; i < 128;  i += 256) wts[WO_B23 + i] = ldf(pb23, i, f32);
    for (int i = t; i < 288;  i += 256) wts[WO_AS + i]  = ldf(attS, i, f32);
    for (int i = t; i < 288;  i += 256) wts[WO_AD + i]  = ldf(attD, i, f32);
    for (int i = t; i < 3072; i += 256) wts[WO_KW + i]  = ldf(kW, i, f32);
    for (int i = t; i < 96;   i += 256) wts[WO_KB + i]  = ldf(kb, i, f32);
    for (int i = t; i < 96;   i += 256) wts[WO_Q + i]   = ldf(qv, i, f32);
    for (int i = t; i < 64;   i += 256) wts[WO_LW + i]  = ldf(linW, i, f32);
    for (int i = t; i < 2;    i += 256) wts[WO_LB + i]  = ldf(linb, i, f32);
}

// ========== MERGED layer-1 projection + edge binning (independent work) ==========
// Slot staging keeps csr-precursor writes sequential per reserved run — the
// direct-scatter variant (round 11) cost 2.3x WRITE_SIZE from per-edge random
// 4B writes dirtying whole 64B sectors.
__global__ __launch_bounds__(256) void k_projbin(
        const void* __restrict__ Xa, const void* __restrict__ Xt,
        const float* __restrict__ W, const float* __restrict__ Bv,
        unsigned short* __restrict__ Ha, unsigned short* __restrict__ Ht,
        const float* __restrict__ attD,
        float* __restrict__ ad0, float* __restrict__ ad1, float* __restrict__ ad2,
        const int* __restrict__ flagp,
        const int* __restrict__ eat_s, const int* __restrict__ eat_d,
        const int* __restrict__ eta_s, const int* __restrict__ eta_d,
        const int* __restrict__ eaa_s, const int* __restrict__ eaa_d,
        int* __restrict__ gcnt,
        int* __restrict__ slot_at, int* __restrict__ slot_ta, int* __restrict__ slot_aa) {
    __shared__ float smem[4224];     // proj: Xs[32*68] + Wl[64*32]; bin: hist[P_AT]
    const int t = threadIdx.x;
    int b = blockIdx.x;
    if (b < NBBIN) {
        // ---------------- bin path ----------------
        int* hist = (int*)smem;
        const int *src, *dst; int E, P, seg; int* slot;
        if (b < CB_AT)              { src = eat_s; dst = eat_d; E = E_AT; P = P_AT; seg = 0;            slot = slot_at; }
        else if (b < CB_AT + CB_TA) { b -= CB_AT;  src = eta_s; dst = eta_d; E = E_TA; P = P_TA; seg = P_AT;        slot = slot_ta; }
        else                        { b -= CB_AT + CB_TA; src = eaa_s; dst = eaa_d; E = E_AA; P = P_AA; seg = P_AT + P_TA; slot = slot_aa; }
        long e0 = (long)b * CHK;
        for (int i = t; i < P; i += 256) hist[i] = 0;
        __syncthreads();
        for (int k = 0; k < CHK; k += 256) {
            long e = e0 + k + t;
            if (e < E) atomicAdd(&hist[dst[e] >> 9], 1);
        }
        __syncthreads();
        for (int i = t; i < P; i += 256) {
            int v = hist[i];
            hist[i] = atomicAdd(&gcnt[seg + i], v);
        }
        __syncthreads();
        for (int k = 0; k < CHK; k += 256) {
            long e = e0 + k + t;
            if (e < E) {
                int d = dst[e];
                int bin = d >> 9;
                int pos = atomicAdd(&hist[bin], 1);
                slot[bin * CAP + pos] = ((d & 511) << 18) | src[e];
            }
        }
        return;
    }
    // ---------------- proj path (K=64, layer 1) ----------------
    b -= NBBIN;
    constexpr int K = 64, XS = K + 4, CPR = K / 4, TOT4 = 32 * CPR;
    float* Xs = smem;                // 32*68 = 2176
    float* Wl = smem + 2176;         // 64*32 = 2048
    const bool isA = b < GA32;
    const int bb = isA ? b : b - GA32;
    const int N = isA ? NA : NT;
    const int wOff = isA ? 0 : 2048;
    const int bOff = isA ? 0 : 32;
    const long n0 = (long)bb * 32;
    for (int i = t; i < K * 32; i += 256) Wl[i] = W[wOff + i];
    {
        const void* X = isA ? Xa : Xt;
        const int f32 = *flagp;
        if (f32) {
            const float* Xf = (const float*)X;
            for (int i = t; i < TOT4; i += 256) {
                int r = i / CPR, c = (i & (CPR - 1)) * 4;
                long gr = n0 + r; if (gr >= N) gr = N - 1;
                *(float4*)&Xs[r * XS + c] = *(const float4*)&Xf[gr * K + c];
            }
        } else {
            const unsigned short* Xh = (const unsigned short*)X;
            for (int i = t; i < TOT4; i += 256) {
                int r = i / CPR, c = (i & (CPR - 1)) * 4;
                long gr = n0 + r; if (gr >= N) gr = N - 1;
                ushort4 v = *(const ushort4*)&Xh[gr * K + c];
                float4 o;
                o.x = bf2f(v.x); o.y = bf2f(v.y); o.z = bf2f(v.z); o.w = bf2f(v.w);
                *(float4*)&Xs[r * XS + c] = o;
            }
        }
    }
    __syncthreads();
    const int g = t >> 3, q = t & 7;
    const long n = n0 + g;
    float a0 = Bv[bOff + q * 4 + 0];
    float a1 = Bv[bOff + q * 4 + 1];
    float a2 = Bv[bOff + q * 4 + 2];
    float a3 = Bv[bOff + q * 4 + 3];
#pragma unroll 4
    for (int k4 = 0; k4 < K; k4 += 4) {
        float4 xv = *(const float4*)&Xs[g * XS + k4];
        float4 w0 = *(const float4*)&Wl[(k4 + 0) * 32 + q * 4];
        float4 w1 = *(const float4*)&Wl[(k4 + 1) * 32 + q * 4];
        float4 w2 = *(const float4*)&Wl[(k4 + 2) * 32 + q * 4];
        float4 w3 = *(const float4*)&Wl[(k4 + 3) * 32 + q * 4];
        a0 = fmaf(xv.x, w0.x, a0); a1 = fmaf(xv.x, w0.y, a1);
        a2 = fmaf(xv.x, w0.z, a2); a3 = fmaf(xv.x, w0.w, a3);
        a0 = fmaf(xv.y, w1.x, a0); a1 = fmaf(xv.y, w1.y, a1);
        a2 = fmaf(xv.y, w1.z, a2); a3 = fmaf(xv.y, w1.w, a3);
        a0 = fmaf(xv.z, w2.x, a0); a1 = fmaf(xv.z, w2.y, a1);
        a2 = fmaf(xv.z, w2.z, a2); a3 = fmaf(xv.z, w2.w, a3);
        a0 = fmaf(xv.w, w3.x, a0); a1 = fmaf(xv.w, w3.y, a1);
        a2 = fmaf(xv.w, w3.z, a2); a3 = fmaf(xv.w, w3.w, a3);
    }
    if (n < N) {
        unsigned short* Hh = isA ? Ha : Ht;
        unsigned int p01 = (unsigned)f2h(a0) | ((unsigned)f2h(a1) << 16);
        unsigned int p23 = (unsigned)f2h(a2) | ((unsigned)f2h(a3) << 16);
        *(uint2*)&Hh[n * 32 + q * 4] = make_uint2(p01, p23);
        const int hh = q >> 1;
        const int ai = q * 4;        // lBase = 0 for layer 1
        if (isA) {
            float p1 = a0 * attD[ai + 32] + a1 * attD[ai + 33]
                     + a2 * attD[ai + 34] + a3 * attD[ai + 35];
            float p2 = a0 * attD[ai + 64] + a1 * attD[ai + 65]
                     + a2 * attD[ai + 66] + a3 * attD[ai + 67];
            float s1 = p1 + __shfl_xor(p1, 1);
            float s2 = p2 + __shfl_xor(p2, 1);
            if (!(q & 1)) { ad1[n * 4 + hh] = s1; ad2[n * 4 + hh] = s2; }
        } else {
            float p0 = a0 * attD[ai] + a1 * attD[ai + 1]
                     + a2 * attD[ai + 2] + a3 * attD[ai + 3];
            float s0 = p0 + __shfl_xor(p0, 1);
            if (!(q & 1)) ad0[n * 4 + hh] = s0;
        }
    }
}

// ========== layers 2/3 projection (K=32, 2 nodes/thread, inline semantic attn) ==========
// 2-node register blocking: lane q computes the q-quad for nodes g and g+32,
// sharing the 4 W reads -> per-node LDS reads drop 80->48; two independent FMA
// chains double ILP. LDS = 64*36 + 1024 floats ~= 13 KB.
__global__ __launch_bounds__(256) void k_proj2(
        const float* __restrict__ O1, const float* __restrict__ Ot,
        const float* __restrict__ O2, const float* __restrict__ semL,
        const float* __restrict__ W, int wOffA, int wOffT,
        const float* __restrict__ Bv, int bOffA, int bOffT,
        unsigned short* __restrict__ Ha, unsigned short* __restrict__ Ht,
        const float* __restrict__ attD, int lBase,
        float* __restrict__ ad0, float* __restrict__ ad1, float* __restrict__ ad2) {
    constexpr int K = 32, XS = K + 4, CPR = K / 4, TOT4 = 64 * CPR;
    __shared__ float Xs[64 * XS];
    __shared__ float Wl[K * 32];
    const int t = threadIdx.x;
    const bool isA = blockIdx.x < GA64;
    const int bb = isA ? (int)blockIdx.x : (int)blockIdx.x - GA64;
    const int N = isA ? NA : NT;
    const int wOff = isA ? wOffA : wOffT;
    const int bOff = isA ? bOffA : bOffT;
    const long n0 = (long)bb * 64;
    for (int i = t; i < K * 32; i += 256) Wl[i] = W[wOff + i];
    if (isA) {
        float s0 = semL[0] * (1.0f / NA), s1 = semL[1] * (1.0f / NA);
        float m = fmaxf(s0, s1);
        float e0 = __expf(s0 - m), e1 = __expf(s1 - m);
        float inv = 1.f / (e0 + e1);
        const float w0 = e0 * inv, w1 = e1 * inv;
        for (int i = t; i < TOT4; i += 256) {
            int r = i / CPR, c = (i & (CPR - 1)) * 4;
            long gr = n0 + r; if (gr >= N) gr = N - 1;
            float4 va = *(const float4*)&O1[gr * K + c];
            float4 vb = *(const float4*)&O2[gr * K + c];
            float4 o;
            o.x = fmaxf(w0 * va.x + w1 * vb.x, 0.f);
            o.y = fmaxf(w0 * va.y + w1 * vb.y, 0.f);
            o.z = fmaxf(w0 * va.z + w1 * vb.z, 0.f);
            o.w = fmaxf(w0 * va.w + w1 * vb.w, 0.f);
            *(float4*)&Xs[r * XS + c] = o;
        }
    } else {
        for (int i = t; i < TOT4; i += 256) {
            int r = i / CPR, c = (i & (CPR - 1)) * 4;
            long gr = n0 + r; if (gr >= N) gr = N - 1;
            *(float4*)&Xs[r * XS + c] = *(const float4*)&Ot[gr * K + c];
        }
    }
    __syncthreads();
    const int g = t >> 3, q = t & 7;
    const long nA = n0 + g, nB = n0 + g + 32;
    float A0 = Bv[bOff + q * 4 + 0], A1 = Bv[bOff + q * 4 + 1];
    float A2 = Bv[bOff + q * 4 + 2], A3 = Bv[bOff + q * 4 + 3];
    float B0 = A0, B1 = A1, B2 = A2, B3 = A3;
#pragma unroll 2
    for (int k4 = 0; k4 < K; k4 += 4) {
        float4 xa = *(const float4*)&Xs[g * XS + k4];
        float4 xb = *(const float4*)&Xs[(g + 32) * XS + k4];
        float4 w0 = *(const float4*)&Wl[(k4 + 0) * 32 + q * 4];
        float4 w1 = *(const float4*)&Wl[(k4 + 1) * 32 + q * 4];
        float4 w2 = *(const float4*)&Wl[(k4 + 2) * 32 + q * 4];
        float4 w3 = *(const float4*)&Wl[(k4 + 3) * 32 + q * 4];
        A0 = fmaf(xa.x, w0.x, A0); A1 = fmaf(xa.x, w0.y, A1);
        A2 = fmaf(xa.x, w0.z, A2); A3 = fmaf(xa.x, w0.w, A3);
        B0 = fmaf(xb.x, w0.x, B0); B1 = fmaf(xb.x, w0.y, B1);
        B2 = fmaf(xb.x, w0.z, B2); B3 = fmaf(xb.x, w0.w, B3);
        A0 = fmaf(xa.y, w1.x, A0); A1 = fmaf(xa.y, w1.y, A1);
        A2 = fmaf(xa.y, w1.z, A2); A3 = fmaf(xa.y, w1.w, A3);
        B0 = fmaf(xb.y, w1.x, B0); B1 = fmaf(xb.y, w1.y, B1);
        B2 = fmaf(xb.y, w1.z, B2); B3 = fmaf(xb.y, w1.w, B3);
        A0 = fmaf(xa.z, w2.x, A0); A1 = fmaf(xa.z, w2.y, A1);
        A2 = fmaf(xa.z, w2.z, A2); A3 = fmaf(xa.z, w2.w, A3);
        B0 = fmaf(xb.z, w2.x, B0); B1 = fmaf(xb.z, w2.y, B1);
        B2 = fmaf(xb.z, w2.z, B2); B3 = fmaf(xb.z, w2.w, B3);
        A0 = fmaf(xa.w, w3.x, A0); A1 = fmaf(xa.w, w3.y, A1);
        A2 = fmaf(xa.w, w3.z, A2); A3 = fmaf(xa.w, w3.w, A3);
        B0 = fmaf(xb.w, w3.x, B0); B1 = fmaf(xb.w, w3.y, B1);
        B2 = fmaf(xb.w, w3.z, B2); B3 = fmaf(xb.w, w3.w, B3);
    }
    const int hh = q >> 1;
    const int ai = lBase + q * 4;
    unsigned short* Hh = isA ? Ha : Ht;
    if (nA < N) {
        unsigned int p01 = (unsigned)f2h(A0) | ((unsigned)f2h(A1) << 16);
        unsigned int p23 = (unsigned)f2h(A2) | ((unsigned)f2h(A3) << 16);
        *(uint2*)&Hh[nA * 32 + q * 4] = make_uint2(p01, p23);
        if (isA) {
            float p1 = A0 * attD[ai + 32] + A1 * attD[ai + 33]
                     + A2 * attD[ai + 34] + A3 * attD[ai + 35];
            float p2 = A0 * attD[ai + 64] + A1 * attD[ai + 65]
                     + A2 * attD[ai + 66] + A3 * attD[ai + 67];
            float s1 = p1 + __shfl_xor(p1, 1);
            float s2 = p2 + __shfl_xor(p2, 1);
            if (!(q & 1)) { ad1[nA * 4 + hh] = s1; ad2[nA * 4 + hh] = s2; }
        } else {
            float p0 = A0 * attD[ai] + A1 * attD[ai + 1]
                     + A2 * attD[ai + 2] + A3 * attD[ai + 3];
            float s0 = p0 + __shfl_xor(p0, 1);
            if (!(q & 1)) ad0[nA * 4 + hh] = s0;
        }
    }
    if (nB < N) {
        unsigned int p01 = (unsigned)f2h(B0) | ((unsigned)f2h(B1) << 16);
        unsigned int p23 = (unsigned)f2h(B2) | ((unsigned)f2h(B3) << 16);
        *(uint2*)&Hh[nB * 32 + q * 4] = make_uint2(p01, p23);
        if (isA) {
            float p1 = B0 * attD[ai + 32] + B1 * attD[ai + 33]
                     + B2 * attD[ai + 34] + B3 * attD[ai + 35];
            float p2 = B0 * attD[ai + 64] + B1 * attD[ai + 65]
                     + B2 * attD[ai + 66] + B3 * attD[ai + 67];
            float s1 = p1 + __shfl_xor(p1, 1);
            float s2 = p2 + __shfl_xor(p2, 1);
            if (!(q & 1)) { ad1[nB * 4 + hh] = s1; ad2[nB * 4 + hh] = s2; }
        } else {
            float p0 = B0 * attD[ai] + B1 * attD[ai + 1]
                     + B2 * attD[ai + 2] + B3 * attD[ai + 3];
            float s0 = p0 + __shfl_xor(p0, 1);
            if (!(q & 1)) ad0[nB * 4 + hh] = s0;
        }
    }
}

// Phase B: per-bin LDS counting sort -> exact CSR + off. The bin's base offset
// is computed in-kernel (sum of gcnt[seg..seg+bin), L2-hot) — no binscan pass.
__global__ __launch_bounds__(256) void k_binsort(
        const int* __restrict__ gcnt,
        const int* __restrict__ slot_at, const int* __restrict__ slot_ta,
        const int* __restrict__ slot_aa,
        int* __restrict__ off_at, int* __restrict__ off_ta, int* __restrict__ off_aa,
        int* __restrict__ csr_at, int* __restrict__ csr_ta, int* __restrict__ csr_aa) {
    __shared__ int sa[512], sb[512], cur[512];
    __shared__ int red[4];
    int b = blockIdx.x, t = threadIdx.x;
    const int* slot; int* off; int* csr; int N, bin, seg;
    if (b < P_AT)              { slot = slot_at; off = off_at; csr = csr_at; N = NT; bin = b;                seg = 0; }
    else if (b < P_AT + P_TA)  { slot = slot_ta; off = off_ta; csr = csr_ta; N = NA; bin = b - P_AT;         seg = P_AT; }
    else                       { slot = slot_aa; off = off_aa; csr = csr_aa; N = NA; bin = b - P_AT - P_TA;  seg = P_AT + P_TA; }
    if (b == 0 && t == 0) { off_at[NT] = E_AT; off_ta[NA] = E_TA; off_aa[NA] = E_AA; }
    // base = exclusive prefix of gcnt over this relation's bins
    int part = 0;
    for (int i = t; i < bin; i += 256) part += gcnt[seg + i];
    for (int o = 32; o > 0; o >>= 1) part += __shfl_xor(part, o, 64);
    if ((t & 63) == 0) red[t >> 6] = part;
    sa[t] = 0; sa[t + 256] = 0;
    __syncthreads();
    const int base = red[0] + red[1] + red[2] + red[3];
    const int cnt  = gcnt[seg + bin];
    const int* sp = &slot[bin * CAP];
    for (int i = t; i < cnt; i += 256) atomicAdd(&sa[sp[i] >> 18], 1);
    __syncthreads();
    int* in = sa; int* out = sb;
    for (int o = 1; o < 512; o <<= 1) {
        for (int i = t; i < 512; i += 256)
            out[i] = in[i] + (i >= o ? in[i - o] : 0);
        __syncthreads();
        int* tmp = in; in = out; out = tmp;
    }
    for (int i = t; i < 512; i += 256) {
        int excl = i ? in[i - 1] : 0;
        cur[i] = excl;
        int gd = bin * 512 + i;
        if (gd < N) off[gd] = base + excl;
    }
    __syncthreads();
    for (int i = t; i < cnt; i += 256) {
        int pk = sp[i];
        int pos = atomicAdd(&cur[pk >> 18], 1);
        csr[base + pos] = pk & 0x3FFFF;
    }
}

// ========== tri-relation gather: 8 lanes/dst, fp16 H, in-kernel src alpha ==========
__global__ __launch_bounds__(256) void k_gather3(
        const int* __restrict__ off_at, const int* __restrict__ csr_at,
        const int* __restrict__ off_ta, const int* __restrict__ csr_ta,
        const int* __restrict__ off_aa, const int* __restrict__ csr_aa,
        const float* __restrict__ ad0, const float* __restrict__ ad1,
        const float* __restrict__ ad2,
        const unsigned short* __restrict__ h_a, const unsigned short* __restrict__ h_t,
        float* __restrict__ o_tx, float* __restrict__ o_a1, float* __restrict__ o_a2,
        const float* __restrict__ attS, int lBase, int gbAT) {
    int b = blockIdx.x;
    const int *off, *csr;
    const float *ad_;
    const unsigned short* Hs;
    float* O;
    int N, attOff;
    if (b < gbAT) {
        off = off_at; csr = csr_at; ad_ = ad0; Hs = h_a; O = o_tx; N = NT;
        attOff = lBase;            // edge type 0 (A->T)
    } else if (b < gbAT + GB_TA) {
        b -= gbAT;
        off = off_ta; csr = csr_ta; ad_ = ad1; Hs = h_t; O = o_a1; N = NA;
        attOff = lBase + 32;       // edge type 1 (T->A)
    } else {
        b -= gbAT + GB_TA;
        off = off_aa; csr = csr_aa; ad_ = ad2; Hs = h_a; O = o_a2; N = NA;
        attOff = lBase + 64;       // edge type 2 (A->A)
    }
    const int t = threadIdx.x;
    const int q = t & 7;          // column quad 0..7
    const int hh = q >> 1;        // head
    const int n = b * 32 + (t >> 3);
    if (n >= N) return;
    const float4 aq = *(const float4*)&attS[attOff + q * 4];
    const float aq0 = aq.x, aq1 = aq.y, aq2 = aq.z, aq3 = aq.w;
    const float adv = ad_[n * 4 + hh];
    const int p0 = off[n], p1 = off[n + 1];
    float ax = 0.f, ay = 0.f, az = 0.f, aw = 0.f, se = 0.f;
    int p = p0;
    for (; p + 4 <= p1; p += 4) {
        int s0 = csr[p], s1 = csr[p + 1], s2 = csr[p + 2], s3 = csr[p + 3];
        ushort4 v0 = *(const ushort4*)&Hs[s0 * 32 + q * 4];
        ushort4 v1 = *(const ushort4*)&Hs[s1 * 32 + q * 4];
        ushort4 v2 = *(const ushort4*)&Hs[s2 * 32 + q * 4];
        ushort4 v3 = *(const ushort4*)&Hs[s3 * 32 + q * 4];
        float h00 = h2f(v0.x), h01 = h2f(v0.y), h02 = h2f(v0.z), h03 = h2f(v0.w);
        float h10 = h2f(v1.x), h11 = h2f(v1.y), h12 = h2f(v1.z), h13 = h2f(v1.w);
        float h20 = h2f(v2.x), h21 = h2f(v2.y), h22 = h2f(v2.z), h23 = h2f(v2.w);
        float h30 = h2f(v3.x), h31 = h2f(v3.y), h32 = h2f(v3.z), h33 = h2f(v3.w);
        float pt0 = h00 * aq0 + h01 * aq1 + h02 * aq2 + h03 * aq3;
        float pt1 = h10 * aq0 + h11 * aq1 + h12 * aq2 + h13 * aq3;
        float pt2 = h20 * aq0 + h21 * aq1 + h22 * aq2 + h23 * aq3;
        float pt3 = h30 * aq0 + h31 * aq1 + h32 * aq2 + h33 * aq3;
        float al0 = pt0 + __shfl_xor(pt0, 1);
        float al1 = pt1 + __shfl_xor(pt1, 1);
        float al2 = pt2 + __shfl_xor(pt2, 1);
        float al3 = pt3 + __shfl_xor(pt3, 1);
        float l0 = al0 + adv; l0 = fmaxf(l0, 0.2f * l0); float e0 = __expf(l0);
        float l1 = al1 + adv; l1 = fmaxf(l1, 0.2f * l1); float e1 = __expf(l1);
        float l2 = al2 + adv; l2 = fmaxf(l2, 0.2f * l2); float e2 = __expf(l2);
        float l3 = al3 + adv; l3 = fmaxf(l3, 0.2f * l3); float e3 = __expf(l3);
        se += e0 + e1 + e2 + e3;
        ax += e0 * h00 + e1 * h10 + e2 * h20 + e3 * h30;
        ay += e0 * h01 + e1 * h11 + e2 * h21 + e3 * h31;
        az += e0 * h02 + e1 * h12 + e2 * h22 + e3 * h32;
        aw += e0 * h03 + e1 * h13 + e2 * h23 + e3 * h33;
    }
    for (; p < p1; p++) {
        int s = csr[p];
        ushort4 v = *(const ushort4*)&Hs[s * 32 + q * 4];
        float h0 = h2f(v.x), h1 = h2f(v.y), h2 = h2f(v.z), h3 = h2f(v.w);
        float pt = h0 * aq0 + h1 * aq1 + h2 * aq2 + h3 * aq3;
        float al = pt + __shfl_xor(pt, 1);
        float l = al + adv; l = fmaxf(l, 0.2f * l);
        float e = __expf(l);
        se += e;
        ax += e * h0; ay += e * h1; az += e * h2; aw += e * h3;
    }
    const float inv = 1.f / (se + 1e-16f);
    float4 r;
    r.x = fmaxf(ax * inv, 0.f);
    r.y = fmaxf(ay * inv, 0.f);
    r.z = fmaxf(az * inv, 0.f);
    r.w = fmaxf(aw * inv, 0.f);
    *(float4*)&O[n * 32 + q * 4] = r;
}

// ---------- semantic reduce: scalar form (includes the q-dot); wave-uniform w ----------
__global__ __launch_bounds__(256) void k_sem_reduce(
        const float* __restrict__ O1, const float* __restrict__ O2,
        const float* __restrict__ kWl, const float* __restrict__ kbl,
        const float* __restrict__ qvl, float* __restrict__ semL) {
    __shared__ float w[1088];        // kW(1024) + kb(32) + qv(32)
    __shared__ float bacc;
    const int t = threadIdx.x;
    const int r = (blockIdx.x >= NB_SEM) ? 1 : 0;
    const float* O = r ? O2 : O1;
    for (int i = t; i < 1024; i += 256) w[i] = kWl[i];
    if (t < 32) w[1024 + t] = kbl[t];
    if (t >= 64 && t < 96) w[1056 + (t - 64)] = qvl[t - 64];
    if (t == 0) bacc = 0.f;
    __syncthreads();
    long n = (long)(blockIdx.x - r * NB_SEM) * 256 + t;
    float S = 0.f;
    if (n < NA) {
        float x[32];
#pragma unroll
        for (int k = 0; k < 32; k++) x[k] = O[n * 32 + k];
#pragma unroll
        for (int f = 0; f < 32; f++) {
            float acc = w[1024 + f];
#pragma unroll
            for (int k = 0; k < 32; k++) acc += x[k] * w[k * 32 + f];
            S += ftanh(acc) * w[1056 + f];
        }
    }
    for (int o = 32; o > 0; o >>= 1) S += __shfl_xor(S, o, 64);
    if ((t & 63) == 0) atomicAdd(&bacc, S);
    __syncthreads();
    if (t == 0) atomicAdd(&semL[r], bacc);
}

// ---------- fused combine + final linear (layer 3 only, inline semantic attn) ----------
__global__ void k_combine_final(const float* __restrict__ o1, const float* __restrict__ o2,
                                const float* __restrict__ semL,
                                const float* __restrict__ linW, const float* __restrict__ linb,
                                void* __restrict__ out, int N, const int* __restrict__ flagp) {
    int n = blockIdx.x * blockDim.x + threadIdx.x;
    if (n >= N) return;
    int f32 = *flagp;
    float q0 = semL[0] * (1.0f / NA), q1 = semL[1] * (1.0f / NA);
    float m = fmaxf(q0, q1);
    float e0 = __expf(q0 - m), e1 = __expf(q1 - m);
    float ai = 1.f / (e0 + e1);
    float w0 = e0 * ai, w1 = e1 * ai;
    float s0 = linb[0], s1 = linb[1];
    const float* p1 = &o1[(long)n * 32];
    const float* p2 = &o2[(long)n * 32];
#pragma unroll
    for (int f = 0; f < 32; f++) {
        float v = w0 * p1[f] + w1 * p2[f];
        v = (v > 0.f) ? v : 0.f;
        s0 += v * linW[f * 2];
        s1 += v * linW[f * 2 + 1];
    }
    if (f32) { ((float*)out)[n * 2] = s0; ((float*)out)[n * 2 + 1] = s1; }
    else {
        ((__hip_bfloat16*)out)[n * 2] = __float2bfloat16(s0);
        ((__hip_bfloat16*)out)[n * 2 + 1] = __float2bfloat16(s1);
    }
}

static inline int gblocks(long n) { return (int)((n + 255) / 256); }

extern "C" void kernel_launch(void* const* d_in, const int* in_sizes, int n_in,
                              void* d_out, int out_size, void* d_ws, size_t ws_size,
                              hipStream_t stream) {
    const void* x_addr = d_in[0];
    const void* x_tx   = d_in[1];
    const int* eat_s = (const int*)d_in[2];
    const int* eat_d = (const int*)d_in[3];
    const int* eta_s = (const int*)d_in[4];
    const int* eta_d = (const int*)d_in[5];
    const int* eaa_s = (const int*)d_in[6];
    const int* eaa_d = (const int*)d_in[7];
    const void* pW1  = d_in[8];
    const void* pb1  = d_in[9];
    const void* pW23 = d_in[10];
    const void* pb23 = d_in[11];
    const void* attS = d_in[12];
    const void* attD = d_in[13];
    const void* kW   = d_in[14];
    const void* kb   = d_in[15];
    const void* qv   = d_in[16];
    const void* linW = d_in[17];
    const void* linb = d_in[18];

    const size_t NA32 = (size_t)NA * 32, NT32 = (size_t)NT * 32;
    const size_t NA4 = (size_t)NA * 4, NT4 = (size_t)NT * 4;

    float* ws    = (float*)d_ws;
    float* h_aF  = ws;                   // fp16 rows (uses half the slot)
    float* h_tF  = h_aF + NA32;
    float* o_a1  = h_tF + NT32;
    float* o_a2  = o_a1 + NA32;
    float* o_tx  = o_a2 + NA32;
    float* ad1   = o_tx + NT32;          // TA dst alphas (addr)
    float* ad2   = ad1 + NA4;            // AA dst alphas (addr)
    float* ad0   = ad2 + NA4;            // AT dst alphas (tx)
    float* sem   = ad0 + NT4;            // 8 scalars: [2l], [2l+1] per layer
    int*   flagp = (int*)(sem + 8);
    int*   off_at = flagp + 16;          // NT+1
    int*   off_ta = off_at + (NT + 1);   // NA+1
    int*   off_aa = off_ta + (NA + 1);   // NA+1
    int*   csr_at = off_aa + (NA + 1);   // E_AT
    int*   csr_ta = csr_at + E_AT;       // E_TA
    int*   csr_aa = csr_ta + E_TA;       // E_AA
    int*   gcnt   = csr_aa + E_AA;       // 1024
    int*   slot_at = gcnt + 1024;        // P_AT*CAP
    int*   slot_ta = slot_at + P_AT * CAP;
    int*   slot_aa = slot_ta + P_TA * CAP;
    float* wts    = (float*)(slot_aa + (size_t)P_AA * CAP);   // fp32 weight cache

    unsigned short* h_a = (unsigned short*)h_aF;
    unsigned short* h_t = (unsigned short*)h_tF;

    k_init<<<1, 256, 0, stream>>>(x_addr, pW1, pb1, pW23, pb23, attS, attD,
                                  kW, kb, qv, linW, linb, wts, flagp, gcnt, sem);

    // bin (613 blocks) runs concurrently with layer-1 projection (10938 blocks)
    k_projbin<<<NBBIN + GA32 + GT32, 256, 0, stream>>>(
        x_addr, x_tx, wts + WO_W1, wts + WO_B1, h_a, h_t, wts + WO_AD,
        ad0, ad1, ad2, flagp,
        eat_s, eat_d, eta_s, eta_d, eaa_s, eaa_d,
        gcnt, slot_at, slot_ta, slot_aa);
    k_binsort<<<NBINS, 256, 0, stream>>>(gcnt, slot_at, slot_ta, slot_aa,
                                         off_at, off_ta, off_aa, csr_at, csr_ta, csr_aa);

    for (int l = 0; l < 3; l++) {
        if (l > 0) {
            int wi = (l - 1) * 2;
            k_proj2<<<GA64 + GT64, 256, 0, stream>>>(
                o_a1, o_tx, o_a2, sem + 2 * (l - 1),
                wts + WO_W23, (wi + 0) * 1024, (wi + 1) * 1024,
                wts + WO_B23, (wi + 0) * 32, (wi + 1) * 32,
                h_a, h_t, wts + WO_AD, l * 96, ad0, ad1, ad2);
        }
        const int gbAT = (l < 2) ? GB_AT : 0;   // layer-3 AT gather is dead work
        k_gather3<<<gbAT + GB_TA + GB_AA, 256, 0, stream>>>(
            off_at, csr_at, off_ta, csr_ta, off_aa, csr_aa,
            ad0, ad1, ad2, h_a, h_t, o_tx, o_a1, o_a2, wts + WO_AS, l * 96, gbAT);
        k_sem_reduce<<<2 * NB_SEM, 256, 0, stream>>>(
            o_a1, o_a2, wts + WO_KW + l * 1024, wts + WO_KB + l * 32,
            wts + WO_Q + l * 32, sem + 2 * l);
        if (l == 2) {
            k_combine_final<<<gblocks(NA), 256, 0, stream>>>(o_a1, o_a2, sem + 4,
                                                             wts + WO_LW, wts + WO_LB,
                                                             d_out, NA, flagp);
        }
    }
}